// Round 14
// baseline (36.875 us; speedup 1.0000x reference)
//
#include <hip/hip_runtime.h>
#include <math.h>

#define TS 49
#define LOG49 3.8918202981106265f
#define LN2 0.6931471805599453f

typedef short bf16x8 __attribute__((ext_vector_type(8)));  // 8 bf16 = 4 VGPRs
typedef float f32x4 __attribute__((ext_vector_type(4)));
typedef float f32x4u __attribute__((ext_vector_type(4), aligned(4)));
typedef unsigned u32x4 __attribute__((ext_vector_type(4)));

// Position labeling: position p holds original state (p+1)%49 -> emission col = p.
// E stored as the A-operand of D = E * V (rows = pos_out, cols(k) = pos_in with
// custom labeling kappa chosen so D's C-layout IS the next step's B-fragment):
//   A row r = 16*nt + (lane&15); hw k = 32h + 8*(lane>>4) + s
//   kappa(32h + 8G + s) = 32h + 16*(s>>2) + 4G + (s&3)
// ws layout: bf16[nt=4][h=2][lane=64][s=8] (8 KB), then float Tmax at byte 8192.

__global__ void prep_kernel(const float* __restrict__ tf, const float* __restrict__ w2,
                            const float* __restrict__ b2, float* __restrict__ ws) {
    __shared__ float tr[TS * TS];
    __shared__ float red[256];
    const int tid = threadIdx.x;
    const float w0 = w2[0], w1 = w2[1], w2v = w2[2], w3 = w2[3], w4 = w2[4], w5 = w2[5];
    const float bb = b2[0];
    float lmax = -INFINITY;
    for (int idx = tid; idx < TS * TS; idx += 256) {
        const float* p = tf + idx * 6;
        float s = bb + p[0]*w0 + p[1]*w1 + p[2]*w2v + p[3]*w3 + p[4]*w4 + p[5]*w5;
        tr[idx] = s;
        lmax = fmaxf(lmax, s);
    }
    red[tid] = lmax;
    __syncthreads();
    for (int s = 128; s > 0; s >>= 1) {
        if (tid < s) red[tid] = fmaxf(red[tid], red[tid + s]);
        __syncthreads();
    }
    const float Tmax = red[0];
    __syncthreads();
    unsigned short* B = (unsigned short*)ws;
    for (int idx = tid; idx < 4096; idx += 256) {
        const int s  = idx & 7;
        const int l  = (idx >> 3) & 63;
        const int h  = (idx >> 9) & 1;
        const int nt = idx >> 10;
        const int G  = l >> 4, c0 = l & 15;
        const int r  = 16 * nt + c0;                              // output position
        const int kp = 32 * h + 16 * (s >> 2) + 4 * G + (s & 3);  // input position
        float v = 0.0f;
        if (r < TS && kp < TS) {
            const int jj = (r + 1) % TS, kk = (kp + 1) % TS;
            v = __expf(tr[jj * TS + kk] - Tmax);
        }
        unsigned bts = __float_as_uint(v);
        B[idx] = (unsigned short)((bts + 0x7FFFu + ((bts >> 16) & 1u)) >> 16);  // rne bf16
    }
    if (tid == 0) ((float*)ws)[2048] = Tmax;  // byte 8192
}

__device__ __forceinline__ unsigned cvtpk_bf16(float lo, float hi) {
    unsigned d;  // D[15:0]=bf16(lo), D[31:16]=bf16(hi)
    asm("v_cvt_pk_bf16_f32 %0, %1, %2" : "=v"(d) : "v"(lo), "v"(hi));
    return d;
}

// One wave = 16 chains (chain = lane&15 = c0). State in C-layout regs v[nt][t]:
// position 16nt + 4G + t (G = lane>>4), chain c0. No LDS, no cross-lane in the loop:
// the C-layout fragment is bit-identical (after bf16 pack) to the next B-fragment.
__global__ __launch_bounds__(64, 1) void crf_fwd(const float* __restrict__ emis,
                                                 const unsigned short* __restrict__ wsE,
                                                 float* __restrict__ out, int L) {
    const int l = threadIdx.x, G = l >> 4, c0 = l & 15;
    const int b0 = blockIdx.x * 16;
    const float Tmax = ((const float*)wsE)[2048];

    // E A-fragments, register-resident
    bf16x8 E[4][2];
    {
        const bf16x8* Et = (const bf16x8*)wsE;
        #pragma unroll
        for (int nt = 0; nt < 4; ++nt)
            #pragma unroll
            for (int h = 0; h < 2; ++h) E[nt][h] = Et[(nt * 2 + h) * 64 + l];
    }

    // Emission bases: chain c0, col chunks {4G, 16+4G, 32+4G, 45} (all in-row).
    const int LT = L * TS;
    const float* const ebase = emis + (size_t)(b0 + c0) * LT;
    const int cb[4] = {4 * G, 16 + 4 * G, 32 + 4 * G, 45};

    f32x4 pf[4][4];  // [slot][nt], statically indexed only

#define LQ(STEP, SLOT) do {                                                           \
    const int _o = (STEP) * TS;                                                       \
    pf[SLOT][0] = *(const f32x4u*)(ebase + _o + cb[0]);                               \
    pf[SLOT][1] = *(const f32x4u*)(ebase + _o + cb[1]);                               \
    pf[SLOT][2] = *(const f32x4u*)(ebase + _o + cb[2]);                               \
    pf[SLOT][3] = *(const f32x4u*)(ebase + _o + cb[3]);                               \
} while (0)

    // ee for a step: nt<=2 all live (pos <= 47); nt=3: only (G=0,t=0)=pos48 matters,
    // its value sits at elem 3 of the col-45 chunk; dead entries get e3 too (acc=0).
#define EESEL(DST, SLOT) do {                                                         \
    _Pragma("unroll")                                                                 \
    for (int t = 0; t < 4; ++t) {                                                     \
        DST[0][t] = __expf(pf[SLOT][0][t]);                                           \
        DST[1][t] = __expf(pf[SLOT][1][t]);                                           \
        DST[2][t] = __expf(pf[SLOT][2][t]);                                           \
    }                                                                                 \
    const float e3_ = __expf(pf[SLOT][3].w);                                          \
    _Pragma("unroll")                                                                 \
    for (int t = 0; t < 4; ++t) DST[3][t] = e3_;                                      \
} while (0)

    f32x4 acc[4];      // E @ V_{I-1}, tile nt
    float v[4][4];     // V_I
    float ee0[4][4], ee1[4][4];
    float sc = 0.f, fac = 1.f, pend = 0.f;

    // pack v (C-layout) -> B-frags (identity relabeling) + 8 MFMAs -> acc
#define PACKMM() do {                                                                 \
    u32x4 Bu0, Bu1;                                                                   \
    Bu0.x = cvtpk_bf16(v[0][0], v[0][1]);                                             \
    Bu0.y = cvtpk_bf16(v[0][2], v[0][3]);                                             \
    Bu0.z = cvtpk_bf16(v[1][0], v[1][1]);                                             \
    Bu0.w = cvtpk_bf16(v[1][2], v[1][3]);                                             \
    Bu1.x = cvtpk_bf16(v[2][0], v[2][1]);                                             \
    Bu1.y = cvtpk_bf16(v[2][2], v[2][3]);                                             \
    Bu1.z = cvtpk_bf16(v[3][0], v[3][1]);                                             \
    Bu1.w = cvtpk_bf16(v[3][2], v[3][3]);                                             \
    const bf16x8 B0 = __builtin_bit_cast(bf16x8, Bu0);                                \
    const bf16x8 B1 = __builtin_bit_cast(bf16x8, Bu1);                                \
    const f32x4 z_ = {0.f, 0.f, 0.f, 0.f};                                            \
    _Pragma("unroll")                                                                 \
    for (int nt = 0; nt < 4; ++nt) {                                                  \
        f32x4 a = __builtin_amdgcn_mfma_f32_16x16x32_bf16(E[nt][0], B0, z_, 0, 0, 0); \
        a = __builtin_amdgcn_mfma_f32_16x16x32_bf16(E[nt][1], B1, a, 0, 0, 0);        \
        acc[nt] = a;                                                                  \
    }                                                                                 \
} while (0)

#define RENC() do {                                                                   \
    float mx = v[0][0];                                                               \
    _Pragma("unroll")                                                                 \
    for (int nt = 0; nt < 4; ++nt)                                                    \
        _Pragma("unroll")                                                             \
        for (int t = 0; t < 4; ++t) mx = fmaxf(mx, v[nt][t]);                         \
    mx = fmaxf(mx, __shfl_xor(mx, 16, 64));                                           \
    mx = fmaxf(mx, __shfl_xor(mx, 32, 64));                                           \
    const unsigned ex = __float_as_uint(mx) >> 23;                                    \
    fac  = __uint_as_float((254u - ex) << 23);                                        \
    pend = (float)((int)ex - 127) * LN2;                                              \
} while (0)

#define STEP(I, EC, EN, SN, SL, DO_C, DO_A) do {                                      \
    if ((I) + 3 < L) LQ((I) + 3, SL);        /* earliest issue -> max slack */        \
    _Pragma("unroll")                                                                 \
    for (int nt = 0; nt < 4; ++nt)                                                    \
        _Pragma("unroll")                                                             \
        for (int t = 0; t < 4; ++t) {                                                 \
            float nv = acc[nt][t] * EC[nt][t];                                        \
            if (DO_A) nv *= fac;                                                      \
            v[nt][t] = nv;                                                            \
        }                                                                             \
    if (DO_A) sc += pend;                                                             \
    PACKMM();                                                                         \
    EESEL(EN, SN);      /* exps overlap MFMA execution */                             \
    asm volatile("" ::: "memory");  /* anchor this step's loads */                    \
    if (DO_C) RENC();                                                                 \
} while (0)

    // prologue: slots 0..3 = steps 0..3
    LQ(0, 0);
    if (L > 1) LQ(1, 1);
    if (L > 2) LQ(2, 2);
    if (L > 3) LQ(3, 3);

    // init V_0 = exp(emit[0][pos]); dead positions (49..63) = 0
    #pragma unroll
    for (int t = 0; t < 4; ++t) {
        v[0][t] = __expf(pf[0][0][t]);
        v[1][t] = __expf(pf[0][1][t]);
        v[2][t] = __expf(pf[0][2][t]);
        v[3][t] = (G == 0 && t == 0) ? __expf(pf[0][3].w) : 0.0f;
    }
    EESEL(ee1, 1);  // ee for step 1
    PACKMM();       // acc = E @ V_0
    asm volatile("" ::: "memory");

    const int S = L - 1;  // steps 1..S
    int i = 1;
    for (; i + 3 <= S; i += 4) {  // i == 1 mod 4 -> static pf slots
        STEP(i + 0, ee1, ee0, 2, 0, 1, 0);
        STEP(i + 1, ee0, ee1, 3, 1, 0, 1);
        STEP(i + 2, ee1, ee0, 0, 2, 0, 0);
        STEP(i + 3, ee0, ee1, 1, 3, 0, 0);
    }
    if (i <= S)     STEP(i,     ee1, ee0, 2, 0, 1, 0);
    if (i + 1 <= S) STEP(i + 1, ee0, ee1, 3, 1, 0, 1);
    if (i + 2 <= S) STEP(i + 2, ee1, ee0, 0, 2, 0, 0);
#undef STEP
#undef RENC
#undef PACKMM
#undef EESEL
#undef LQ

    // final: alpha[chain c0] = sc + log(sum_pos V) + LOG49 + (L-1)*Tmax
    float s = 0.0f;
    #pragma unroll
    for (int nt = 0; nt < 4; ++nt)
        #pragma unroll
        for (int t = 0; t < 4; ++t) s += v[nt][t];
    s += __shfl_xor(s, 16, 64);
    s += __shfl_xor(s, 32, 64);
    const float res = sc + __logf(s) + LOG49 + (float)(L - 1) * Tmax;
    if (l < 16) out[b0 + c0] = res;
}

extern "C" void kernel_launch(void* const* d_in, const int* in_sizes, int n_in,
                              void* d_out, int out_size, void* d_ws, size_t ws_size,
                              hipStream_t stream) {
    const float* emis = (const float*)d_in[0];
    const float* tf   = (const float*)d_in[1];
    const float* w2   = (const float*)d_in[2];
    const float* b2   = (const float*)d_in[3];
    float* out = (float*)d_out;
    float* ws  = (float*)d_ws;

    const int B = out_size;                // 8192
    const int L = in_sizes[0] / (B * TS);  // 48

    prep_kernel<<<1, 256, 0, stream>>>(tf, w2, b2, ws);
    crf_fwd<<<B / 16, 64, 0, stream>>>(emis, (const unsigned short*)ws, out, L);
}